// Round 3
// baseline (88.942 us; speedup 1.0000x reference)
//
#include <hip/hip_runtime.h>

// GAT block, algebraically collapsed:
//   d[b,f,n]   = softmax_n( x[b,:,f,n] . (W @ a2) )[n] * mask[n,n]
//   out[b,h,f,n] = d[b,f,n] * (sum_c x[b,c,f,n]*W[c,h] + bW[h])
// (s1, ab, bW.a2 cancel inside the row-softmax — constant over the softmax axis.)
//
// Two-kernel split: K1 computes d (6.55 MB) into ws; K2 is a pure streaming
// writer (1 float4 output slot per thread, 64 h-iterations, nontemporal stores).

typedef float vfloat4 __attribute__((ext_vector_type(4)));

namespace {
constexpr int B_ = 32, C_ = 3, F_ = 2048, N_ = 25, H_ = 64;
constexpr int FN = F_ * N_;          // 51200
constexpr int FN4 = FN / 4;          // 12800 float4 slots per (b,c)/(b,h) plane
constexpr int TF = 64;               // frames per K1 block tile
constexpr int TPOS = TF * N_;        // 1600
constexpr int TVEC = TPOS / 4;       // 400
constexpr int THREADS = 256;
constexpr size_t D_BYTES = (size_t)B_ * FN * sizeof(float);  // 6.55 MB
}

// ---------------- K1: diag-scale d[b, f*n] -> ws ----------------
__global__ __launch_bounds__(THREADS) void gat_diag(
    const float* __restrict__ x, const float* __restrict__ mask,
    const float* __restrict__ W, const float* __restrict__ a2,
    float* __restrict__ dout)
{
  __shared__ vfloat4 x4[3 * TVEC];
  __shared__ vfloat4 d4[TVEC];
  __shared__ float mdl[N_];
  __shared__ float wal[C_];

  const int tid = threadIdx.x;
  const int blk = blockIdx.x;
  const int b  = blk >> 5;
  const int ft = blk & 31;
  const size_t fbase = (size_t)ft * TPOS;

  if (tid < N_) mdl[tid] = mask[tid * N_ + tid];
  if (tid >= 64 && tid < 64 + C_) {          // separate wave from mask loads
    const int c = tid - 64;
    float s = 0.f;
    for (int h = 0; h < H_; ++h) s += W[c * H_ + h] * a2[h];
    wal[c] = s;
  }

  const vfloat4* xg = (const vfloat4*)x;
  for (int i = tid; i < 3 * TVEC; i += THREADS) {
    int c = i / TVEC;
    int j = i - c * TVEC;
    x4[i] = xg[(size_t)(b * 3 + c) * FN4 + (fbase >> 2) + j];
  }
  __syncthreads();

  if (tid < TF) {
    const float* xl = (const float*)x4;
    const float wa0 = wal[0], wa1 = wal[1], wa2 = wal[2];
    const int base = tid * N_;
    float s[N_];
    float m = -3.0e38f;
#pragma unroll
    for (int n = 0; n < N_; ++n) {
      float v = fmaf(xl[2 * TPOS + base + n], wa2,
                fmaf(xl[TPOS + base + n], wa1, xl[base + n] * wa0));
      s[n] = v;
      m = fmaxf(m, v);
    }
    float z = 0.f;
#pragma unroll
    for (int n = 0; n < N_; ++n) { s[n] = __expf(s[n] - m); z += s[n]; }
    const float inv = 1.f / z;
    float* dl = (float*)d4;
#pragma unroll
    for (int n = 0; n < N_; ++n) dl[base + n] = s[n] * inv * mdl[n];
  }
  __syncthreads();

  vfloat4* dg = (vfloat4*)dout;
  const size_t db = ((size_t)b * FN + fbase) >> 2;
  dg[db + tid] = d4[tid];
  if (tid < TVEC - THREADS) dg[db + THREADS + tid] = d4[THREADS + tid];
}

// ---------------- K2: streaming writer ----------------
__global__ __launch_bounds__(THREADS) void gat_write(
    const float* __restrict__ x, const float* __restrict__ d,
    const float* __restrict__ W, const float* __restrict__ bW,
    float* __restrict__ out)
{
  __shared__ float Wl[C_ * H_];
  __shared__ float bWl[H_];
  const int tid = threadIdx.x;
  if (tid < C_ * H_) Wl[tid] = W[tid];
  if (tid < H_) bWl[tid] = bW[tid];
  __syncthreads();

  const size_t p = (size_t)blockIdx.x * THREADS + tid;   // 0 .. B*FN4-1
  const int b = (int)(p / FN4);
  const int j = (int)(p - (size_t)b * FN4);

  const vfloat4* xg = (const vfloat4*)x;
  const vfloat4 x0 = xg[(size_t)(b * 3 + 0) * FN4 + j];
  const vfloat4 x1 = xg[(size_t)(b * 3 + 1) * FN4 + j];
  const vfloat4 x2 = xg[(size_t)(b * 3 + 2) * FN4 + j];
  const vfloat4 dd = ((const vfloat4*)d)[p];

  vfloat4* og = (vfloat4*)out;
  const size_t ob = (size_t)b * H_ * FN4 + j;
#pragma unroll 4
  for (int h = 0; h < H_; ++h) {
    const float w0 = Wl[h], w1 = Wl[H_ + h], w2 = Wl[2 * H_ + h], bw = bWl[h];
    vfloat4 o;
    o.x = dd.x * fmaf(x2.x, w2, fmaf(x1.x, w1, fmaf(x0.x, w0, bw)));
    o.y = dd.y * fmaf(x2.y, w2, fmaf(x1.y, w1, fmaf(x0.y, w0, bw)));
    o.z = dd.z * fmaf(x2.z, w2, fmaf(x1.z, w1, fmaf(x0.z, w0, bw)));
    o.w = dd.w * fmaf(x2.w, w2, fmaf(x1.w, w1, fmaf(x0.w, w0, bw)));
    __builtin_nontemporal_store(o, &og[ob + (size_t)h * FN4]);
  }
}

// ---------------- fallback: fused kernel (no ws needed) ----------------
__global__ __launch_bounds__(THREADS) void gat_fused(
    const float* __restrict__ x, const float* __restrict__ mask,
    const float* __restrict__ W, const float* __restrict__ bW,
    const float* __restrict__ a2, float* __restrict__ out)
{
  __shared__ vfloat4 x4[3 * TVEC];
  __shared__ vfloat4 d4[TVEC];
  __shared__ float Wl[C_ * H_];
  __shared__ float bWl[H_];
  __shared__ float a2l[H_];
  __shared__ float mdl[N_];
  __shared__ float wal[C_];

  const int tid = threadIdx.x;
  const int blk = blockIdx.x;
  const int b  = blk >> 5;
  const int ft = blk & 31;
  const size_t fbase = (size_t)ft * TPOS;

  if (tid < C_ * H_) Wl[tid] = W[tid];
  if (tid < H_) { bWl[tid] = bW[tid]; a2l[tid] = a2[tid]; }
  if (tid < N_) mdl[tid] = mask[tid * N_ + tid];

  const vfloat4* xg = (const vfloat4*)x;
  for (int i = tid; i < 3 * TVEC; i += THREADS) {
    int c = i / TVEC;
    int j = i - c * TVEC;
    x4[i] = xg[(size_t)(b * 3 + c) * FN4 + (fbase >> 2) + j];
  }
  __syncthreads();

  if (tid < C_) {
    float s = 0.f;
    for (int h = 0; h < H_; ++h) s += Wl[tid * H_ + h] * a2l[h];
    wal[tid] = s;
  }
  __syncthreads();

  if (tid < TF) {
    const float* xl = (const float*)x4;
    const float wa0 = wal[0], wa1 = wal[1], wa2 = wal[2];
    const int base = tid * N_;
    float s[N_];
    float m = -3.0e38f;
#pragma unroll
    for (int n = 0; n < N_; ++n) {
      float v = fmaf(xl[2 * TPOS + base + n], wa2,
                fmaf(xl[TPOS + base + n], wa1, xl[base + n] * wa0));
      s[n] = v;
      m = fmaxf(m, v);
    }
    float z = 0.f;
#pragma unroll
    for (int n = 0; n < N_; ++n) { s[n] = __expf(s[n] - m); z += s[n]; }
    const float inv = 1.f / z;
    float* dl = (float*)d4;
#pragma unroll
    for (int n = 0; n < N_; ++n) dl[base + n] = s[n] * inv * mdl[n];
  }
  __syncthreads();

  const bool has2 = (tid + THREADS) < TVEC;
  const vfloat4 xa0 = x4[tid];
  const vfloat4 xa1 = x4[TVEC + tid];
  const vfloat4 xa2 = x4[2 * TVEC + tid];
  const vfloat4 da  = d4[tid];
  vfloat4 xb0 = {}, xb1 = {}, xb2 = {}, db = {};
  if (has2) {
    xb0 = x4[tid + THREADS];
    xb1 = x4[TVEC + tid + THREADS];
    xb2 = x4[2 * TVEC + tid + THREADS];
    db  = d4[tid + THREADS];
  }

  vfloat4* og = (vfloat4*)out;
  const size_t ob = ((size_t)b * H_ * FN + fbase) >> 2;
  for (int h = 0; h < H_; ++h) {
    const float w0 = Wl[h], w1 = Wl[H_ + h], w2 = Wl[2 * H_ + h], bw = bWl[h];
    const size_t vb = ob + (size_t)h * FN4;
    vfloat4 o;
    o.x = da.x * fmaf(xa2.x, w2, fmaf(xa1.x, w1, fmaf(xa0.x, w0, bw)));
    o.y = da.y * fmaf(xa2.y, w2, fmaf(xa1.y, w1, fmaf(xa0.y, w0, bw)));
    o.z = da.z * fmaf(xa2.z, w2, fmaf(xa1.z, w1, fmaf(xa0.z, w0, bw)));
    o.w = da.w * fmaf(xa2.w, w2, fmaf(xa1.w, w1, fmaf(xa0.w, w0, bw)));
    og[vb + tid] = o;
    if (has2) {
      vfloat4 o2;
      o2.x = db.x * fmaf(xb2.x, w2, fmaf(xb1.x, w1, fmaf(xb0.x, w0, bw)));
      o2.y = db.y * fmaf(xb2.y, w2, fmaf(xb1.y, w1, fmaf(xb0.y, w0, bw)));
      o2.z = db.z * fmaf(xb2.z, w2, fmaf(xb1.z, w1, fmaf(xb0.z, w0, bw)));
      o2.w = db.w * fmaf(xb2.w, w2, fmaf(xb1.w, w1, fmaf(xb0.w, w0, bw)));
      og[vb + tid + THREADS] = o2;
    }
  }
}

extern "C" void kernel_launch(void* const* d_in, const int* in_sizes, int n_in,
                              void* d_out, int out_size, void* d_ws, size_t ws_size,
                              hipStream_t stream) {
  const float* x    = (const float*)d_in[0];  // [B,C,F,N]
  const float* mask = (const float*)d_in[1];  // [N,N]
  const float* W    = (const float*)d_in[2];  // [C,H]
  const float* bW   = (const float*)d_in[3];  // [H]
  // d_in[4] = a1 (cancels), d_in[6] = ab (cancels)
  const float* a2   = (const float*)d_in[5];  // [H]
  float* out = (float*)d_out;                 // [B,H,F,N]

  if (ws_size >= D_BYTES && d_ws != nullptr) {
    float* d = (float*)d_ws;
    hipLaunchKernelGGL(gat_diag, dim3(B_ * (F_ / TF)), dim3(THREADS), 0, stream,
                       x, mask, W, a2, d);
    hipLaunchKernelGGL(gat_write, dim3(B_ * FN4 / THREADS), dim3(THREADS), 0, stream,
                       x, d, W, bW, out);
  } else {
    hipLaunchKernelGGL(gat_fused, dim3(B_ * (F_ / TF)), dim3(THREADS), 0, stream,
                       x, mask, W, bW, a2, out);
  }
}

// Round 4
// 81.363 us; speedup vs baseline: 1.0932x; 1.0932x over previous
//
#include <hip/hip_runtime.h>

// GAT block, algebraically collapsed:
//   d[b,f,n]     = softmax_n( x[b,:,f,n] . (W @ a2) )[n] * mask[n,n]
//   out[b,h,f,n] = d[b,f,n] * (sum_c x[b,c,f,n]*W[c,h] + bW[h])
// (s1, ab, bW.a2 cancel inside the row-softmax — constant over the softmax axis.)
//
// Single fused kernel: each block owns 256 consecutive float4 output slots of
// one batch plane. It stages its x window (+frame halo) in LDS, computes the
// <=42 row-softmaxes in one wave, then streams 64 h-planes of nontemporal
// float4 stores with x/d held in registers (read once from HBM).

typedef float vfloat4 __attribute__((ext_vector_type(4)));

namespace {
constexpr int B_ = 32, C_ = 3, F_ = 2048, N_ = 25, H_ = 64;
constexpr int FN   = F_ * N_;      // 51200 floats per (b,c)/(b,h) plane
constexpr int FN4  = FN / 4;       // 12800 float4 slots per plane
constexpr int THREADS = 256;
constexpr int JB   = FN4 / THREADS; // 50 blocks per plane
constexpr int MAXW = 264;          // max float4 window per channel (<=1056 floats)
}

__global__ __launch_bounds__(THREADS) void gat_fused2(
    const float* __restrict__ x, const float* __restrict__ mask,
    const float* __restrict__ W, const float* __restrict__ bW,
    const float* __restrict__ a2, float* __restrict__ out)
{
  __shared__ float   xl[3][4 * MAXW];   // x window, per channel
  __shared__ float   dl[4 * MAXW];      // diag-scale per position in window
  __shared__ vfloat4 Wp[H_];            // {W0[h], W1[h], W2[h], bW[h]}
  __shared__ float   mdl[N_];
  __shared__ float   wal[C_];

  const int tid = threadIdx.x;
  const int blk = blockIdx.x;
  const int b   = blk / JB;
  const int jb  = blk - b * JB;
  const int S   = jb * THREADS;         // float4 slot base within plane
  const int p0  = S * 4;                // first float position of this block
  const int f0  = p0 / N_;
  const int f1  = (p0 + 4 * THREADS - 1) / N_;
  const int nf  = f1 - f0 + 1;          // <= 42 frames
  const int A0  = (f0 * N_) & ~3;       // aligned window start (floats)
  int A1 = (f1 * N_ + N_ + 3) & ~3;     // aligned window end
  if (A1 > FN) A1 = FN;
  const int cnt4 = (A1 - A0) >> 2;      // <= MAXW

  // ---- stage: x window -> LDS; pack W; wa = W@a2; mask diag ----
  const vfloat4* xg = (const vfloat4*)x;
#pragma unroll
  for (int c = 0; c < 3; ++c) {
    const vfloat4* src = xg + (size_t)(b * 3 + c) * FN4 + (A0 >> 2);
    vfloat4* dst = (vfloat4*)xl[c];
    for (int i = tid; i < cnt4; i += THREADS) dst[i] = src[i];
  }
  if (tid < H_) {
    vfloat4 w = {W[tid], W[H_ + tid], W[2 * H_ + tid], bW[tid]};
    Wp[tid] = w;
  } else if (tid < H_ + C_) {
    const int c = tid - H_;
    float s = 0.f;
    for (int h = 0; h < H_; ++h) s += W[c * H_ + h] * a2[h];
    wal[c] = s;
  }
  if (tid >= 128 && tid < 128 + N_) mdl[tid - 128] = mask[(tid - 128) * (N_ + 1)];
  __syncthreads();

  // ---- per-frame 25-way softmax -> dl (one wave covers all <=42 frames) ----
  if (tid < nf) {
    const float wa0 = wal[0], wa1 = wal[1], wa2 = wal[2];
    const int base = (f0 + tid) * N_ - A0;
    float s[N_];
    float m = -3.0e38f;
#pragma unroll
    for (int n = 0; n < N_; ++n) {
      float v = fmaf(xl[2][base + n], wa2,
                fmaf(xl[1][base + n], wa1, xl[0][base + n] * wa0));
      s[n] = v;
      m = fmaxf(m, v);
    }
    float z = 0.f;
#pragma unroll
    for (int n = 0; n < N_; ++n) { s[n] = __expf(s[n] - m); z += s[n]; }
    const float inv = 1.f / z;
#pragma unroll
    for (int n = 0; n < N_; ++n) dl[base + n] = s[n] * inv * mdl[n];
  }
  __syncthreads();

  // ---- write phase: x/d in registers, 64 nontemporal float4 stores ----
  const int li = tid + S - (A0 >> 2);   // this thread's float4 index in window
  const vfloat4 x0 = ((const vfloat4*)xl[0])[li];
  const vfloat4 x1 = ((const vfloat4*)xl[1])[li];
  const vfloat4 x2 = ((const vfloat4*)xl[2])[li];
  const vfloat4 dd = ((const vfloat4*)dl)[li];

  vfloat4* og = (vfloat4*)out;
  const size_t ob = (size_t)b * H_ * FN4 + S + tid;
#pragma unroll 4
  for (int h = 0; h < H_; ++h) {
    const vfloat4 wv = Wp[h];            // one broadcast ds_read_b128
    vfloat4 o;
    o.x = dd.x * fmaf(x2.x, wv.z, fmaf(x1.x, wv.y, fmaf(x0.x, wv.x, wv.w)));
    o.y = dd.y * fmaf(x2.y, wv.z, fmaf(x1.y, wv.y, fmaf(x0.y, wv.x, wv.w)));
    o.z = dd.z * fmaf(x2.z, wv.z, fmaf(x1.z, wv.y, fmaf(x0.z, wv.x, wv.w)));
    o.w = dd.w * fmaf(x2.w, wv.z, fmaf(x1.w, wv.y, fmaf(x0.w, wv.x, wv.w)));
    __builtin_nontemporal_store(o, &og[ob + (size_t)h * FN4]);
  }
}

extern "C" void kernel_launch(void* const* d_in, const int* in_sizes, int n_in,
                              void* d_out, int out_size, void* d_ws, size_t ws_size,
                              hipStream_t stream) {
  const float* x    = (const float*)d_in[0];  // [B,C,F,N]
  const float* mask = (const float*)d_in[1];  // [N,N]
  const float* W    = (const float*)d_in[2];  // [C,H]
  const float* bW   = (const float*)d_in[3];  // [H]
  // d_in[4] = a1 (cancels), d_in[6] = ab (cancels)
  const float* a2   = (const float*)d_in[5];  // [H]
  float* out = (float*)d_out;                 // [B,H,F,N]

  hipLaunchKernelGGL(gat_fused2, dim3(B_ * JB), dim3(THREADS), 0, stream,
                     x, mask, W, bW, a2, out);
}